// Round 7
// baseline (819.655 us; speedup 1.0000x reference)
//
#include <hip/hip_runtime.h>

// ---------------------------------------------------------------------------
// LSTMDecoder: 3 chained LSTM cells + edge FC + 3-head attention + heads.
// B=1024, H=768, S=256, C=(202,183,11).
// R7: ONE plain kernel, 512 blocks (guaranteed co-resident: LDS 48KB -> 3
// blocks/CU cap, launch_bounds(256,2) -> need 2/CU), software grid barrier
// (agent-scope atomics + __threadfence, the grid.sync() recipe) instead of
// hipLaunchCooperativeKernel (which failed to launch in R6). Math identical
// to R5 (passed, absmax 3.9e-3): fp16 MFMA, 4-buffer counted-vmcnt kloop,
// fused LSTM-cell epilogues, fused coalesced fp32 attention.
// ---------------------------------------------------------------------------

typedef unsigned short u16;
typedef _Float16       f16x8 __attribute__((ext_vector_type(8)));
typedef float          f32x4 __attribute__((ext_vector_type(4)));

#define NBLK 512u
#define SWZ(r) ((((r) + ((r) >> 2))) & 3)
#define VMCNT(N) asm volatile("s_waitcnt vmcnt(" #N ")" ::: "memory")
#define KBAR()  do { __builtin_amdgcn_s_barrier(); __builtin_amdgcn_sched_barrier(0); } while (0)

__device__ __forceinline__ u16 f2h(float f) {
  _Float16 h = (_Float16)f;
  return __builtin_bit_cast(u16, h);
}
__device__ __forceinline__ float sigm(float x) { return 1.f / (1.f + __expf(-x)); }
__device__ __forceinline__ float ftanh(float x) { return 1.f - 2.f / (__expf(2.f * x) + 1.f); }

__device__ __forceinline__ void gld16(const u16* g, u16* l) {
  __builtin_amdgcn_global_load_lds(
      (const __attribute__((address_space(1))) unsigned int*)(g),
      (__attribute__((address_space(3))) unsigned int*)(l),
      16, 0, 0);
}

// ---- software grid barrier (generation/sense-reversal; agent scope) ------
__device__ __forceinline__ void gbar(unsigned* bar, int tid) {
  __syncthreads();
  if (tid == 0) {
    __threadfence();   // release: my block's stores -> visible device-wide
    unsigned g = __hip_atomic_load(bar + 1, __ATOMIC_RELAXED, __HIP_MEMORY_SCOPE_AGENT);
    unsigned a = __hip_atomic_fetch_add(bar, 1u, __ATOMIC_ACQ_REL, __HIP_MEMORY_SCOPE_AGENT);
    if (a == NBLK - 1u) {
      __hip_atomic_store(bar, 0u, __ATOMIC_RELAXED, __HIP_MEMORY_SCOPE_AGENT);
      __hip_atomic_fetch_add(bar + 1, 1u, __ATOMIC_RELEASE, __HIP_MEMORY_SCOPE_AGENT);
    } else {
      while (__hip_atomic_load(bar + 1, __ATOMIC_RELAXED, __HIP_MEMORY_SCOPE_AGENT) == g)
        __builtin_amdgcn_s_sleep(2);
    }
    __threadfence();   // acquire: other blocks' stores -> visible to me
  }
  __syncthreads();
}

// per-thread staging pointers (two K-segments; seg2 when kt >= ntA)
struct KP { const u16 *pA1, *pA2, *pW1_0, *pW2_0, *pW1_1, *pW2_1; };

__device__ __forceinline__ void stage_tile(const KP& kp, int kt, int ntA,
                                           u16* Asb, u16* Bsb, int wv) {
  const bool s1 = (kt < ntA);
  const int off = (s1 ? kt : kt - ntA) * 32;
  gld16((s1 ? kp.pA1   : kp.pA2  ) + off, Asb + wv * 512);
  gld16((s1 ? kp.pW1_0 : kp.pW2_0) + off, Bsb + wv * 512);
  gld16((s1 ? kp.pW1_1 : kp.pW2_1) + off, Bsb + 2048 + wv * 512);
}

__device__ __forceinline__ void compute_tile(const u16* Asb, const u16* Bsb,
                                             int wv, int frow, int fsl, f32x4* acc) {
  const int ar = wv * 16 + frow;
  f16x8 ah = *(const f16x8*)(Asb + ar * 32 + ((fsl ^ SWZ(ar)) * 8));
  f16x8 bh[8];
#pragma unroll
  for (int n = 0; n < 8; ++n) {
    const int br = n * 16 + frow;
    bh[n] = *(const f16x8*)(Bsb + br * 32 + ((fsl ^ SWZ(br)) * 8));
  }
#pragma unroll
  for (int n = 0; n < 8; ++n)
    acc[n] = __builtin_amdgcn_mfma_f32_16x16x32_f16(ah, bh[n], acc[n], 0, 0, 0);
}

// 4-buffer depth-2 counted-vmcnt pipeline over NT k-tiles (R5-identical)
__device__ __forceinline__ void kloop4(const KP& kp, int ntA, int NT,
                                       u16* As, u16* Bs,
                                       int wv, int frow, int fsl, f32x4* acc) {
  stage_tile(kp, 0, ntA, As,        Bs,        wv);
  stage_tile(kp, 1, ntA, As + 2048, Bs + 4096, wv);
  stage_tile(kp, 2, ntA, As + 4096, Bs + 8192, wv);
  for (int t = 0; t < NT - 2; ++t) {
    VMCNT(6); KBAR();
    const int cb = t & 3;
    compute_tile(As + cb * 2048, Bs + cb * 4096, wv, frow, fsl, acc);
    if (t + 3 < NT) {
      const int sb = (t + 3) & 3;
      stage_tile(kp, t + 3, ntA, As + sb * 2048, Bs + sb * 4096, wv);
    }
  }
  VMCNT(3); KBAR();
  compute_tile(As + ((NT - 2) & 3) * 2048, Bs + ((NT - 2) & 3) * 4096,
               wv, frow, fsl, acc);
  VMCNT(0); KBAR();
  compute_tile(As + ((NT - 1) & 3) * 2048, Bs + ((NT - 1) & 3) * 4096,
               wv, frow, fsl, acc);
}

// ---------------------------------------------------------------------------
struct GJob {
  const u16* A; const u16* W;
  float* outf; u16* outh;
  const float* bias; const float* bias2; const float* addend;
  int N; int ldc; int relu;
};

// plain GEMM tile: out[64 x 128] at (bm0,bn0); W row-major [N x 768]
__device__ __forceinline__ void run_gemm(const GJob& jb, int bx, int by,
                                         u16* As, u16* Bs, int tid) {
  const int bn0 = bx * 128;
  if (bn0 >= jb.N) return;
  const int bm0 = by * 64;
  const int lane = tid & 63, wv = tid >> 6;
  const int frow = lane & 15, fsl = lane >> 4;

  const int ra  = tid >> 2,        csa  = (tid & 3) ^ SWZ(ra);
  const int rb1 = (tid >> 2) + 64, csb1 = (tid & 3) ^ SWZ(rb1);
  int wr0 = bn0 + ra;  if (wr0 >= jb.N) wr0 = jb.N - 1;
  int wr1 = bn0 + rb1; if (wr1 >= jb.N) wr1 = jb.N - 1;

  KP kp;
  kp.pA1 = kp.pA2 = jb.A + (size_t)(bm0 + ra) * 768 + csa * 8;
  kp.pW1_0 = kp.pW2_0 = jb.W + (size_t)wr0 * 768 + csa * 8;
  kp.pW1_1 = kp.pW2_1 = jb.W + (size_t)wr1 * 768 + csb1 * 8;

  f32x4 acc[8];
#pragma unroll
  for (int n = 0; n < 8; ++n) acc[n] = (f32x4){0.f, 0.f, 0.f, 0.f};

  kloop4(kp, 24, 24, As, Bs, wv, frow, fsl, acc);

  const int rb = (lane >> 4) * 4;
  const int cc = lane & 15;
#pragma unroll
  for (int n = 0; n < 8; ++n) {
    const int col = bn0 + n * 16 + cc;
    if (col >= jb.N) continue;
    float bv = 0.f;
    if (jb.bias)  bv += jb.bias[col];
    if (jb.bias2) bv += jb.bias2[col];
    const int row0 = bm0 + wv * 16 + rb;
#pragma unroll
    for (int r = 0; r < 4; ++r) {
      const int row = row0 + r;
      float v = acc[n][r] + bv;
      if (jb.addend) v += jb.addend[(size_t)row * jb.ldc + col];
      if (jb.relu)   v = fmaxf(v, 0.f);
      if (jb.outf)   jb.outf[(size_t)row * jb.ldc + col] = v;
      if (jb.outh)   jb.outh[(size_t)row * jb.ldc + col] = f2h(v);
    }
  }
}

// LSTM cell tile: gates = [A1|A2]*[W1|W2]^T + bi + bh_, cell math epilogue.
// Gate-stripe B: W row = (r>>5)*768 + bj0 + (r&31), r in [0,128).
__device__ __forceinline__ void run_cell(const u16* A1, const u16* A2,
                                         const u16* W1, const u16* W2,
                                         const float* bi, const float* bh_,
                                         const float* cprev,
                                         float* hf, float* cf, u16* hh, u16* ch,
                                         int NT, int bx, int by,
                                         u16* As, u16* Bs, int tid) {
  const int bj0 = bx * 32;
  const int bm0 = by * 64;
  const int lane = tid & 63, wv = tid >> 6;
  const int frow = lane & 15, fsl = lane >> 4;

  const int ra  = tid >> 2,        csa  = (tid & 3) ^ SWZ(ra);
  const int rb1 = (tid >> 2) + 64, csb1 = (tid & 3) ^ SWZ(rb1);
  const int wr0 = (ra >> 5) * 768 + bj0 + (ra & 31);
  const int wr1 = (rb1 >> 5) * 768 + bj0 + (rb1 & 31);

  KP kp;
  kp.pA1  = A1 + (size_t)(bm0 + ra) * 768 + csa * 8;
  kp.pA2  = A2 + (size_t)(bm0 + ra) * 768 + csa * 8;
  kp.pW1_0 = W1 + (size_t)wr0 * 768 + csa * 8;
  kp.pW2_0 = W2 + (size_t)wr0 * 768 + csa * 8;
  kp.pW1_1 = W1 + (size_t)wr1 * 768 + csb1 * 8;
  kp.pW2_1 = W2 + (size_t)wr1 * 768 + csb1 * 8;

  f32x4 acc[8];
#pragma unroll
  for (int n = 0; n < 8; ++n) acc[n] = (f32x4){0.f, 0.f, 0.f, 0.f};

  kloop4(kp, 24, NT, As, Bs, wv, frow, fsl, acc);

  const int rb = (lane >> 4) * 4;
  const int cc = lane & 15;
#pragma unroll
  for (int jj = 0; jj < 2; ++jj) {
    const int j = bj0 + jj * 16 + cc;
    const float b_i = bi[j]        + bh_[j];
    const float b_f = bi[768 + j]  + bh_[768 + j];
    const float b_g = bi[1536 + j] + bh_[1536 + j];
    const float b_o = bi[2304 + j] + bh_[2304 + j];
    const int row0 = bm0 + wv * 16 + rb;
#pragma unroll
    for (int r = 0; r < 4; ++r) {
      const int row = row0 + r;
      float gi = acc[0 + jj][r] + b_i;
      float gf = acc[2 + jj][r] + b_f;
      float gg = acc[4 + jj][r] + b_g;
      float go = acc[6 + jj][r] + b_o;
      float c = sigm(gi) * ftanh(gg);
      if (cprev) c += sigm(gf) * cprev[row * 768 + j];
      float h = sigm(go) * ftanh(c);
      if (hf) hf[row * 768 + j] = h;
      if (cf) cf[row * 768 + j] = c;
      if (hh) hh[row * 768 + j] = f2h(h);
      if (ch) ch[row * 768 + j] = f2h(c);
    }
  }
}

__device__ __forceinline__ void cvt_seg(const float* s, u16* d, int n4,
                                        int gtid, int nthr) {
  for (int i = gtid; i < n4; i += nthr) {
    float4 v = ((const float4*)s)[i];
    ushort4 h;
    h.x = f2h(v.x); h.y = f2h(v.y); h.z = f2h(v.z); h.w = f2h(v.w);
    ((ushort4*)d)[i] = h;
  }
}

// ---------------------------------------------------------------------------
struct MP {
  const float *x, *attn, *Wih, *Whh, *bih, *bhh, *hfcW, *hfcb, *cfcW, *cfcb;
  const float *midW, *midb, *o1W, *o1b, *o2W, *o2b, *o3W, *o3b;
  float* out;
  float *h1f, *c1f, *h2f, *cp3f, *h3f;
  u16 *xh, *Wihh, *Whhh, *hfch, *cfch, *midh, *o1h, *o2h, *o3h;
  u16 *h1h, *h2h, *c2h, *hp3h, *a1h, *a2h, *a3h, *m1h, *m2h, *m3h;
  unsigned* bar;
};

__global__ __launch_bounds__(256, 2)
void mega_k(MP p)
{
  // LDS union: GEMM {As 16KB | Bs 32KB} vs attn {accW 36864B | lsum 48B}
  __shared__ __align__(16) char smem[49152];
  u16* As = (u16*)smem;
  u16* Bs = (u16*)(smem + 16384);
  float* accW  = (float*)smem;           // [4][3][768]
  float* lsumW = (float*)(smem + 36864); // [4][3]

  const int blk = blockIdx.x, tid = threadIdx.x;
  const int lane = tid & 63, wv = tid >> 6;

  // ---- S0: all fp32->fp16 conversions, full grid ----
  {
    const int g = blk * 256 + tid, N = NBLK * 256;
    cvt_seg(p.x,             p.xh,             196608,  g, N);
    cvt_seg(p.Wih,           p.Wihh,           1769472, g, N);   // all 3 tasks
    cvt_seg(p.Whh + 2359296, p.Whhh,           1179648, g, N);   // Whh[1],Whh[2]
    cvt_seg(p.hfcW,          p.hfch,           147456,  g, N);
    cvt_seg(p.cfcW,          p.cfch,           147456,  g, N);
    cvt_seg(p.midW,          p.midh,           442368,  g, N);
    cvt_seg(p.o1W,           p.o1h,            38784,   g, N);
    cvt_seg(p.o2W,           p.o2h,            35136,   g, N);
    cvt_seg(p.o3W,           p.o3h,            2112,    g, N);
  }
  gbar(p.bar, tid);

  // ---- S1: cell1: gates = x*Wih1^T + bih1 + bhh1 (384 jobs) ----
  if (blk < 384) {
    run_cell(p.xh, p.xh, p.Wihh, p.Wihh, p.bih, p.bhh, nullptr,
             p.h1f, p.c1f, p.h1h, nullptr, 24, blk % 24, blk / 24, As, Bs, tid);
  }
  gbar(p.bar, tid);

  // ---- S2: cell2: gates = [x|h1]*[Wih2|Whh1]^T ----
  if (blk < 384) {
    run_cell(p.xh, p.h1h, p.Wihh + (size_t)3072 * 768, p.Whhh,
             p.bih + 3072, p.bhh + 3072, p.c1f,
             p.h2f, nullptr, p.h2h, p.c2h, 48, blk % 24, blk / 24, As, Bs, tid);
  }
  gbar(p.bar, tid);

  // ---- S3: hp3 = h1 + h2*hfcW^T + hfcb ; cp3 = c1 + c2*cfcW^T + cfcb ----
  if (blk < 192) {
    const int job = blk / 96, r = blk % 96;
    GJob jb;
    if (job == 0) jb = { p.h2h, p.hfch, nullptr, p.hp3h, p.hfcb, nullptr, p.h1f, 768, 768, 0 };
    else          jb = { p.c2h, p.cfch, p.cp3f, nullptr, p.cfcb, nullptr, p.c1f, 768, 768, 0 };
    run_gemm(jb, r % 6, r / 6, As, Bs, tid);
  }
  gbar(p.bar, tid);

  // ---- S4: cell3: gates = [x|hp3]*[Wih3|Whh2]^T ----
  if (blk < 384) {
    run_cell(p.xh, p.hp3h, p.Wihh + (size_t)6144 * 768, p.Whhh + 2359296,
             p.bih + 6144, p.bhh + 6144, p.cp3f,
             p.h3f, nullptr, nullptr, nullptr, 48, blk % 24, blk / 24, As, Bs, tid);
  }
  gbar(p.bar, tid);

  // ---- S5: fused attention, rows blk and blk+512 ----
  for (int rep = 0; rep < 2; ++rep) {
    const int b = blk + rep * NBLK;
    const float* ab = p.attn + (size_t)b * 196608;
    const int cb = lane * 4;

    __syncthreads();   // previous accW/LDS readers done before overwrite

    float4 hh[3][3];
#pragma unroll
    for (int j = 0; j < 3; ++j) {
      hh[0][j] = *(const float4*)(p.h1f + b * 768 + j * 256 + cb);
      hh[1][j] = *(const float4*)(p.h2f + b * 768 + j * 256 + cb);
      hh[2][j] = *(const float4*)(p.h3f + b * 768 + j * 256 + cb);
    }
    float4 acc[3][3];
#pragma unroll
    for (int t3 = 0; t3 < 3; ++t3)
#pragma unroll
      for (int j = 0; j < 3; ++j) acc[t3][j] = (float4){0.f, 0.f, 0.f, 0.f};
    float lsum[3] = {0.f, 0.f, 0.f};

    const int row0 = wv * 64;
    for (int sub = 0; sub < 16; ++sub) {
      const float* rp = ab + (size_t)(row0 + sub * 4) * 768 + cb;
      float4 vv[4][3];
#pragma unroll
      for (int s = 0; s < 4; ++s)
#pragma unroll
        for (int j = 0; j < 3; ++j)
          vv[s][j] = *(const float4*)(rp + s * 768 + j * 256);

      float q[3][4];
#pragma unroll
      for (int t3 = 0; t3 < 3; ++t3)
#pragma unroll
        for (int s = 0; s < 4; ++s) {
          float d = 0.f;
#pragma unroll
          for (int j = 0; j < 3; ++j) {
            d = fmaf(vv[s][j].x, hh[t3][j].x, d);
            d = fmaf(vv[s][j].y, hh[t3][j].y, d);
            d = fmaf(vv[s][j].z, hh[t3][j].z, d);
            d = fmaf(vv[s][j].w, hh[t3][j].w, d);
          }
          q[t3][s] = d;
        }
#pragma unroll
      for (int t3 = 0; t3 < 3; ++t3)
#pragma unroll
        for (int s = 0; s < 4; ++s) {
#pragma unroll
          for (int d = 1; d < 64; d <<= 1)
            q[t3][s] += __shfl_xor(q[t3][s], d);
          q[t3][s] = __expf(q[t3][s]);
        }
#pragma unroll
      for (int t3 = 0; t3 < 3; ++t3)
#pragma unroll
        for (int s = 0; s < 4; ++s) {
          const float pw = q[t3][s];
          lsum[t3] += pw;
#pragma unroll
          for (int j = 0; j < 3; ++j) {
            acc[t3][j].x = fmaf(pw, vv[s][j].x, acc[t3][j].x);
            acc[t3][j].y = fmaf(pw, vv[s][j].y, acc[t3][j].y);
            acc[t3][j].z = fmaf(pw, vv[s][j].z, acc[t3][j].z);
            acc[t3][j].w = fmaf(pw, vv[s][j].w, acc[t3][j].w);
          }
        }
    }

    __syncthreads();
#pragma unroll
    for (int t3 = 0; t3 < 3; ++t3)
#pragma unroll
      for (int j = 0; j < 3; ++j)
        *(float4*)(&accW[(wv * 3 + t3) * 768 + j * 256 + cb]) = acc[t3][j];
    if (lane == 0) {
#pragma unroll
      for (int t3 = 0; t3 < 3; ++t3) lsumW[wv * 3 + t3] = lsum[t3];
    }
    __syncthreads();

    float ltot[3];
#pragma unroll
    for (int t3 = 0; t3 < 3; ++t3)
      ltot[t3] = lsumW[t3] + lsumW[3 + t3] + lsumW[6 + t3] + lsumW[9 + t3];
    u16* outs[3] = { p.a1h, p.a2h, p.a3h };
#pragma unroll
    for (int cc = 0; cc < 3; ++cc) {
      const int c = tid + cc * 256;
#pragma unroll
      for (int t3 = 0; t3 < 3; ++t3) {
        float s = accW[t3 * 768 + c] + accW[(3 + t3) * 768 + c] +
                  accW[(6 + t3) * 768 + c] + accW[(9 + t3) * 768 + c];
        outs[t3][b * 768 + c] = f2h(s / ltot[t3]);
      }
    }
  }
  gbar(p.bar, tid);

  // ---- S6: mid heads: m = relu(a*midW^T + midb) (288 jobs) ----
  if (blk < 288) {
    const int t = blk / 96, r = blk % 96;
    const u16* a = (t == 0) ? p.a1h : (t == 1) ? p.a2h : p.a3h;
    u16*       m = (t == 0) ? p.m1h : (t == 1) ? p.m2h : p.m3h;
    GJob jb = { a, p.midh + (size_t)t * 589824, nullptr, m,
                p.midb + t * 768, nullptr, nullptr, 768, 768, 1 };
    run_gemm(jb, r % 6, r / 6, As, Bs, tid);
  }
  gbar(p.bar, tid);

  // ---- S7: output heads (96 jobs) ----
  if (blk < 96) {
    const int t = blk / 32, r = blk % 32;
    const u16* m = (t == 0) ? p.m1h : (t == 1) ? p.m2h : p.m3h;
    const u16* w = (t == 0) ? p.o1h : (t == 1) ? p.o2h : p.o3h;
    const float* bb = (t == 0) ? p.o1b : (t == 1) ? p.o2b : p.o3b;
    float* o = p.out + ((t == 0) ? 0 : (t == 1) ? 206848 : 394240);
    const int N = (t == 0) ? 202 : (t == 1) ? 183 : 11;
    GJob jb = { m, w, o, nullptr, bb, nullptr, nullptr, N, N, 0 };
    run_gemm(jb, r % 2, r / 2, As, Bs, tid);
  }
}

// ---------------------------------------------------------------------------
extern "C" void kernel_launch(void* const* d_in, const int* in_sizes, int n_in,
                              void* d_out, int out_size, void* d_ws, size_t ws_size,
                              hipStream_t stream)
{
  char* ws = (char*)d_ws;

  MP p;
  p.x    = (const float*)d_in[0];
  p.attn = (const float*)d_in[1];
  p.Wih  = (const float*)d_in[2];
  p.Whh  = (const float*)d_in[3];
  p.bih  = (const float*)d_in[4];
  p.bhh  = (const float*)d_in[5];
  p.hfcW = (const float*)d_in[6];
  p.hfcb = (const float*)d_in[7];
  p.cfcW = (const float*)d_in[8];
  p.cfcb = (const float*)d_in[9];
  p.midW = (const float*)d_in[10];
  p.midb = (const float*)d_in[11];
  p.o1W  = (const float*)d_in[12];
  p.o1b  = (const float*)d_in[13];
  p.o2W  = (const float*)d_in[14];
  p.o2b  = (const float*)d_in[15];
  p.o3W  = (const float*)d_in[16];
  p.o3b  = (const float*)d_in[17];
  p.out  = (float*)d_out;

  p.h1f  = (float*)(ws + 0);
  p.c1f  = (float*)(ws + 3145728);
  p.h2f  = (float*)(ws + 6291456);
  p.cp3f = (float*)(ws + 9437184);
  p.h3f  = (float*)(ws + 12582912);
  p.xh   = (u16*)(ws + 15728640);
  p.Wihh = (u16*)(ws + 17301504);
  p.Whhh = (u16*)(ws + 31457280);
  p.hfch = (u16*)(ws + 40894464);
  p.cfch = (u16*)(ws + 42074112);
  p.midh = (u16*)(ws + 43253760);
  p.o1h  = (u16*)(ws + 46792704);
  p.o2h  = (u16*)(ws + 47102976);
  p.o3h  = (u16*)(ws + 47384064);
  p.h1h  = (u16*)(ws + 47400960);
  p.h2h  = (u16*)(ws + 48973824);
  p.c2h  = (u16*)(ws + 50546688);
  p.hp3h = (u16*)(ws + 52119552);
  p.a1h  = (u16*)(ws + 53692416);
  p.a2h  = (u16*)(ws + 55265280);
  p.a3h  = (u16*)(ws + 56838144);
  p.m1h  = (u16*)(ws + 58411008);
  p.m2h  = (u16*)(ws + 59983872);
  p.m3h  = (u16*)(ws + 61556736);
  p.bar  = (unsigned*)(ws + 63129600);
  // workspace end: 63,129,616 bytes

  hipMemsetAsync(p.bar, 0, 16, stream);   // ws is 0xAA-poisoned; barrier needs 0
  mega_k<<<dim3(NBLK), dim3(256), 0, stream>>>(p);

  (void)in_sizes; (void)n_in; (void)out_size; (void)ws_size;
}

// Round 8
// 318.559 us; speedup vs baseline: 2.5730x; 2.5730x over previous
//
#include <hip/hip_runtime.h>

// ---------------------------------------------------------------------------
// LSTMDecoder: 3 chained LSTM cells + edge FC + 3-head attention + heads.
// B=1024, H=768, S=256, C=(202,183,11).
// R8: back to multi-kernel (R7 mega-kernel = 2.5x regression: 24% occupancy,
// fence-invalidated L2, spin-bound). Chain restructured: K1 runs cell1 in
// parallel with Gpre = x*Wih[2,3]^T (+biases) and the remaining weight
// conversions (block-range split, kernel boundary = sync). cell2/cell3 are
// K=768 GEMMs + fp32 Gpre addend (R3-verified). fp16 MFMA, 4-buffer
// counted-vmcnt pipeline (vmcnt 6/3/0), fused cell epilogues, fused
// coalesced single-pass fp32 attention (R5-verbatim).
// ---------------------------------------------------------------------------

typedef unsigned short u16;
typedef _Float16       f16x8 __attribute__((ext_vector_type(8)));
typedef float          f32x4 __attribute__((ext_vector_type(4)));

#define SWZ(r) ((((r) + ((r) >> 2))) & 3)
#define VMCNT(N) asm volatile("s_waitcnt vmcnt(" #N ")" ::: "memory")
#define KBAR()  do { __builtin_amdgcn_s_barrier(); __builtin_amdgcn_sched_barrier(0); } while (0)

__device__ __forceinline__ u16 f2h(float f) {
  _Float16 h = (_Float16)f;
  return __builtin_bit_cast(u16, h);
}
__device__ __forceinline__ float sigm(float x) { return 1.f / (1.f + __expf(-x)); }
__device__ __forceinline__ float ftanh(float x) { return 1.f - 2.f / (__expf(2.f * x) + 1.f); }

__device__ __forceinline__ void gld16(const u16* g, u16* l) {
  __builtin_amdgcn_global_load_lds(
      (const __attribute__((address_space(1))) unsigned int*)(g),
      (__attribute__((address_space(3))) unsigned int*)(l),
      16, 0, 0);
}

// per-thread staging pointers (single K-segment, K=768, NT=24)
struct KP { const u16 *pA, *pW0, *pW1; };

__device__ __forceinline__ void stage_tile(const KP& kp, int kt,
                                           u16* Asb, u16* Bsb, int wv) {
  const int off = kt * 32;
  gld16(kp.pA  + off, Asb + wv * 512);
  gld16(kp.pW0 + off, Bsb + wv * 512);
  gld16(kp.pW1 + off, Bsb + 2048 + wv * 512);
}

__device__ __forceinline__ void compute_tile(const u16* Asb, const u16* Bsb,
                                             int wv, int frow, int fsl, f32x4* acc) {
  const int ar = wv * 16 + frow;
  f16x8 ah = *(const f16x8*)(Asb + ar * 32 + ((fsl ^ SWZ(ar)) * 8));
  f16x8 bh[8];
#pragma unroll
  for (int n = 0; n < 8; ++n) {
    const int br = n * 16 + frow;
    bh[n] = *(const f16x8*)(Bsb + br * 32 + ((fsl ^ SWZ(br)) * 8));
  }
#pragma unroll
  for (int n = 0; n < 8; ++n)
    acc[n] = __builtin_amdgcn_mfma_f32_16x16x32_f16(ah, bh[n], acc[n], 0, 0, 0);
}

// 4-buffer depth-2 counted-vmcnt pipeline over 24 k-tiles
__device__ __forceinline__ void kloop(const KP& kp, u16* As, u16* Bs,
                                      int wv, int frow, int fsl, f32x4* acc) {
  const int NT = 24;
  stage_tile(kp, 0, As,        Bs,        wv);
  stage_tile(kp, 1, As + 2048, Bs + 4096, wv);
  stage_tile(kp, 2, As + 4096, Bs + 8192, wv);
  for (int t = 0; t < NT - 2; ++t) {
    VMCNT(6); KBAR();
    const int cb = t & 3;
    compute_tile(As + cb * 2048, Bs + cb * 4096, wv, frow, fsl, acc);
    if (t + 3 < NT) {
      const int sb = (t + 3) & 3;
      stage_tile(kp, t + 3, As + sb * 2048, Bs + sb * 4096, wv);
    }
  }
  VMCNT(3); KBAR();
  compute_tile(As + ((NT - 2) & 3) * 2048, Bs + ((NT - 2) & 3) * 4096,
               wv, frow, fsl, acc);
  VMCNT(0); KBAR();
  compute_tile(As + ((NT - 1) & 3) * 2048, Bs + ((NT - 1) & 3) * 4096,
               wv, frow, fsl, acc);
}

// ---------------------------------------------------------------------------
struct GJob {
  const u16* A; const u16* W;
  float* outf; u16* outh;
  const float* bias; const float* bias2; const float* addend;
  int N; int ldc; int relu;
};

// plain GEMM tile: out[64 x 128] at (bm0,bn0); A[1024x768], W row-major [Nx768]
__device__ __forceinline__ void run_gemm(const GJob& jb, int bx, int by,
                                         u16* As, u16* Bs, int tid) {
  const int bn0 = bx * 128;
  if (bn0 >= jb.N) return;
  const int bm0 = by * 64;
  const int lane = tid & 63, wv = tid >> 6;
  const int frow = lane & 15, fsl = lane >> 4;

  const int ra  = tid >> 2,        csa  = (tid & 3) ^ SWZ(ra);
  const int rb1 = (tid >> 2) + 64, csb1 = (tid & 3) ^ SWZ(rb1);
  int wr0 = bn0 + ra;  if (wr0 >= jb.N) wr0 = jb.N - 1;
  int wr1 = bn0 + rb1; if (wr1 >= jb.N) wr1 = jb.N - 1;

  KP kp;
  kp.pA  = jb.A + (size_t)(bm0 + ra) * 768 + csa * 8;
  kp.pW0 = jb.W + (size_t)wr0 * 768 + csa * 8;
  kp.pW1 = jb.W + (size_t)wr1 * 768 + csb1 * 8;

  f32x4 acc[8];
#pragma unroll
  for (int n = 0; n < 8; ++n) acc[n] = (f32x4){0.f, 0.f, 0.f, 0.f};

  kloop(kp, As, Bs, wv, frow, fsl, acc);

  const int rb = (lane >> 4) * 4;
  const int cc = lane & 15;
#pragma unroll
  for (int n = 0; n < 8; ++n) {
    const int col = bn0 + n * 16 + cc;
    if (col >= jb.N) continue;
    float bv = 0.f;
    if (jb.bias)  bv += jb.bias[col];
    if (jb.bias2) bv += jb.bias2[col];
    const int row0 = bm0 + wv * 16 + rb;
#pragma unroll
    for (int r = 0; r < 4; ++r) {
      const int row = row0 + r;
      float v = acc[n][r] + bv;
      if (jb.addend) v += jb.addend[(size_t)row * jb.ldc + col];
      if (jb.relu)   v = fmaxf(v, 0.f);
      if (jb.outf)   jb.outf[(size_t)row * jb.ldc + col] = v;
      if (jb.outh)   jb.outh[(size_t)row * jb.ldc + col] = f2h(v);
    }
  }
}

// LSTM cell tile: gates = A*W^T (+bi+bh | +addend[row*6144 + gate*768 + j]),
// cell math in epilogue. Gate-stripe B: W row = (r>>5)*768 + bj0 + (r&31).
__device__ __forceinline__ void run_cell(const u16* A, const u16* W,
                                         const float* bi, const float* bh_,
                                         const float* addend,
                                         const float* cprev,
                                         float* hf, float* cf, u16* hh, u16* ch,
                                         int bx, int by,
                                         u16* As, u16* Bs, int tid) {
  const int bj0 = bx * 32;
  const int bm0 = by * 64;
  const int lane = tid & 63, wv = tid >> 6;
  const int frow = lane & 15, fsl = lane >> 4;

  const int ra  = tid >> 2,        csa  = (tid & 3) ^ SWZ(ra);
  const int rb1 = (tid >> 2) + 64, csb1 = (tid & 3) ^ SWZ(rb1);
  const int wr0 = (ra >> 5) * 768 + bj0 + (ra & 31);
  const int wr1 = (rb1 >> 5) * 768 + bj0 + (rb1 & 31);

  KP kp;
  kp.pA  = A + (size_t)(bm0 + ra) * 768 + csa * 8;
  kp.pW0 = W + (size_t)wr0 * 768 + csa * 8;
  kp.pW1 = W + (size_t)wr1 * 768 + csb1 * 8;

  f32x4 acc[8];
#pragma unroll
  for (int n = 0; n < 8; ++n) acc[n] = (f32x4){0.f, 0.f, 0.f, 0.f};

  kloop(kp, As, Bs, wv, frow, fsl, acc);

  const int rb = (lane >> 4) * 4;
  const int cc = lane & 15;
#pragma unroll
  for (int jj = 0; jj < 2; ++jj) {
    const int j = bj0 + jj * 16 + cc;
    float b_i = 0.f, b_f = 0.f, b_g = 0.f, b_o = 0.f;
    if (bi) {
      b_i = bi[j]        + bh_[j];
      b_f = bi[768 + j]  + bh_[768 + j];
      b_g = bi[1536 + j] + bh_[1536 + j];
      b_o = bi[2304 + j] + bh_[2304 + j];
    }
    const int row0 = bm0 + wv * 16 + rb;
#pragma unroll
    for (int r = 0; r < 4; ++r) {
      const int row = row0 + r;
      float gi = acc[0 + jj][r] + b_i;
      float gf = acc[2 + jj][r] + b_f;
      float gg = acc[4 + jj][r] + b_g;
      float go = acc[6 + jj][r] + b_o;
      if (addend) {
        const float* ad = addend + (size_t)row * 6144;
        gi += ad[j]; gf += ad[768 + j]; gg += ad[1536 + j]; go += ad[2304 + j];
      }
      float c = sigm(gi) * ftanh(gg);
      if (cprev) c += sigm(gf) * cprev[row * 768 + j];
      float h = sigm(go) * ftanh(c);
      if (hf) hf[row * 768 + j] = h;
      if (cf) cf[row * 768 + j] = c;
      if (hh) hh[row * 768 + j] = f2h(h);
      if (ch) ch[row * 768 + j] = f2h(c);
    }
  }
}

__device__ __forceinline__ void cvt_seg(const float* s, u16* d, int n4,
                                        int gtid, int nthr) {
  for (int i = gtid; i < n4; i += nthr) {
    float4 v = ((const float4*)s)[i];
    ushort4 h;
    h.x = f2h(v.x); h.y = f2h(v.y); h.z = f2h(v.z); h.w = f2h(v.w);
    ((ushort4*)d)[i] = h;
  }
}

// ---------------------------------------------------------------------------
// K0: convert x + all Wih (needed by K1)
__global__ __launch_bounds__(256)
void cvt0_k(const float* x, u16* xh, const float* Wih, u16* Wihh)
{
  const int g = blockIdx.x * 256 + threadIdx.x, N = 2048 * 256;
  cvt_seg(x,   xh,   196608,  g, N);
  cvt_seg(Wih, Wihh, 1769472, g, N);
}

// K1: cell1 (blocks 0..383) || Gpre GEMM (384..1151) || cvt-rest (1152..1535)
struct K1P {
  const u16 *xh, *Wihh;
  const float *bih, *bhh;
  float *h1f, *c1f; u16* h1h;
  float* Gpre;
  const float *Whh, *hfcW, *cfcW, *midW, *o1W, *o2W, *o3W;
  u16 *Whhh, *hfch, *cfch, *midh, *o1h, *o2h, *o3h;
};

__global__ __launch_bounds__(256)
void k1_k(K1P p)
{
  __shared__ __align__(16) u16 As[4 * 64 * 32];    // 16 KB
  __shared__ __align__(16) u16 Bs[4 * 128 * 32];   // 32 KB
  const int blk = blockIdx.x, tid = threadIdx.x;

  if (blk < 384) {
    // cell1: gates = x*Wih1^T + bih1 + bhh1 (no recurrent, no addend)
    run_cell(p.xh, p.Wihh, p.bih, p.bhh, nullptr, nullptr,
             p.h1f, p.c1f, p.h1h, nullptr, blk % 24, blk / 24, As, Bs, tid);
  } else if (blk < 1152) {
    // Gpre = x*Wih[2,3]^T + bih[2,3] + bhh[2,3]   (N=6144)
    const int r = blk - 384;
    GJob jb = { p.xh, p.Wihh + (size_t)3072 * 768, p.Gpre, nullptr,
                p.bih + 3072, p.bhh + 3072, nullptr, 6144, 6144, 0 };
    run_gemm(jb, r % 48, r / 48, As, Bs, tid);
  } else {
    // convert weights needed from K2 onward
    const int g = (blk - 1152) * 256 + tid, N = 384 * 256;
    cvt_seg(p.Whh + 2359296, p.Whhh, 1179648, g, N);   // Whh[1], Whh[2]
    cvt_seg(p.hfcW, p.hfch, 147456, g, N);
    cvt_seg(p.cfcW, p.cfch, 147456, g, N);
    cvt_seg(p.midW, p.midh, 442368, g, N);
    cvt_seg(p.o1W,  p.o1h,  38784,  g, N);
    cvt_seg(p.o2W,  p.o2h,  35136,  g, N);
    cvt_seg(p.o3W,  p.o3h,  2112,   g, N);
  }
}

// K2/K4: LSTM cell with Gpre addend
__global__ __launch_bounds__(256)
void cell_k(const u16* __restrict__ A, const u16* __restrict__ W,
            const float* __restrict__ addend, const float* __restrict__ cprev,
            float* hf, float* cf, u16* hh, u16* ch)
{
  __shared__ __align__(16) u16 As[4 * 64 * 32];
  __shared__ __align__(16) u16 Bs[4 * 128 * 32];
  run_cell(A, W, nullptr, nullptr, addend, cprev, hf, cf, hh, ch,
           blockIdx.x, blockIdx.y, As, Bs, threadIdx.x);
}

// z-batched plain GEMMs (S3 / mid / out)
struct GArgs { GJob j[3]; };

__global__ __launch_bounds__(256)
void gemm_k(GArgs P)
{
  __shared__ __align__(16) u16 As[4 * 64 * 32];
  __shared__ __align__(16) u16 Bs[4 * 128 * 32];
  run_gemm(P.j[blockIdx.z], blockIdx.x, blockIdx.y, As, Bs, threadIdx.x);
}

// ---------------------------------------------------------------------------
// Fused attention, all 3 tasks, single pass over attn (805 MB fp32).
// Block = 4 waves; wave w owns rows [w*64,w*64+64). Lane owns columns
// {256*j + 4*lane + r}: every float4 load is 64 lanes x 16B contiguous.
// Dots wave-local via shfl butterfly; unnormalized exp; one LDS combine.
// ---------------------------------------------------------------------------
__global__ __launch_bounds__(256)
void attn_k(const float* __restrict__ attn,
            const float* __restrict__ h1, const float* __restrict__ h2,
            const float* __restrict__ h3,
            u16* __restrict__ a1, u16* __restrict__ a2, u16* __restrict__ a3)
{
  const int b = blockIdx.x, tid = threadIdx.x;
  const int lane = tid & 63, wv = tid >> 6;
  __shared__ float accW[4][3][768];
  __shared__ float lsumW[4][3];

  const float* ab = attn + (size_t)b * 196608;
  const int cb = lane * 4;

  float4 hh[3][3];
#pragma unroll
  for (int j = 0; j < 3; ++j) {
    hh[0][j] = *(const float4*)(h1 + b * 768 + j * 256 + cb);
    hh[1][j] = *(const float4*)(h2 + b * 768 + j * 256 + cb);
    hh[2][j] = *(const float4*)(h3 + b * 768 + j * 256 + cb);
  }

  float4 acc[3][3];
#pragma unroll
  for (int t3 = 0; t3 < 3; ++t3)
#pragma unroll
    for (int j = 0; j < 3; ++j) acc[t3][j] = (float4){0.f, 0.f, 0.f, 0.f};
  float lsum[3] = {0.f, 0.f, 0.f};

  const int row0 = wv * 64;
  for (int sub = 0; sub < 16; ++sub) {
    const float* rp = ab + (size_t)(row0 + sub * 4) * 768 + cb;
    float4 vv[4][3];
#pragma unroll
    for (int s = 0; s < 4; ++s)
#pragma unroll
      for (int j = 0; j < 3; ++j)
        vv[s][j] = *(const float4*)(rp + s * 768 + j * 256);

    float q[3][4];
#pragma unroll
    for (int t3 = 0; t3 < 3; ++t3)
#pragma unroll
      for (int s = 0; s < 4; ++s) {
        float d = 0.f;
#pragma unroll
        for (int j = 0; j < 3; ++j) {
          d = fmaf(vv[s][j].x, hh[t3][j].x, d);
          d = fmaf(vv[s][j].y, hh[t3][j].y, d);
          d = fmaf(vv[s][j].z, hh[t3][j].z, d);
          d = fmaf(vv[s][j].w, hh[t3][j].w, d);
        }
        q[t3][s] = d;
      }
#pragma unroll
    for (int t3 = 0; t3 < 3; ++t3)
#pragma unroll
      for (int s = 0; s < 4; ++s) {
#pragma unroll
        for (int d = 1; d < 64; d <<= 1)
          q[t3][s] += __shfl_xor(q[t3][s], d);
        q[t3][s] = __expf(q[t3][s]);
      }
#pragma unroll
    for (int t3 = 0; t3 < 3; ++t3)
#pragma unroll
      for (int s = 0; s < 4; ++s) {
        const float pw = q[t3][s];
        lsum[t3] += pw;
#pragma unroll
        for (int j = 0; j < 3; ++j) {
          acc[t3][j].x = fmaf(pw, vv[s][j].x, acc[t3][j].x);
          acc[t3][j].y = fmaf(pw, vv[s][j].y, acc[t3][j].y);
          acc[t3][j].z = fmaf(pw, vv[s][j].z, acc[t3][j].z);
          acc[t3][j].w = fmaf(pw, vv[s][j].w, acc[t3][j].w);
        }
      }
  }

#pragma unroll
  for (int t3 = 0; t3 < 3; ++t3)
#pragma unroll
    for (int j = 0; j < 3; ++j)
      *(float4*)(&accW[wv][t3][j * 256 + cb]) = acc[t3][j];
  if (lane == 0) {
#pragma unroll
    for (int t3 = 0; t3 < 3; ++t3) lsumW[wv][t3] = lsum[t3];
  }
  __syncthreads();

  float ltot[3];
#pragma unroll
  for (int t3 = 0; t3 < 3; ++t3)
    ltot[t3] = lsumW[0][t3] + lsumW[1][t3] + lsumW[2][t3] + lsumW[3][t3];
  u16* outs[3] = { a1, a2, a3 };
#pragma unroll
  for (int cc = 0; cc < 3; ++cc) {
    const int c = tid + cc * 256;
#pragma unroll
    for (int t3 = 0; t3 < 3; ++t3) {
      float s = accW[0][t3][c] + accW[1][t3][c] + accW[2][t3][c] + accW[3][t3][c];
      outs[t3][b * 768 + c] = f2h(s / ltot[t3]);
    }
  }
}

// ---------------------------------------------------------------------------
extern "C" void kernel_launch(void* const* d_in, const int* in_sizes, int n_in,
                              void* d_out, int out_size, void* d_ws, size_t ws_size,
                              hipStream_t stream)
{
  const float* x    = (const float*)d_in[0];
  const float* attn = (const float*)d_in[1];
  const float* Wih  = (const float*)d_in[2];
  const float* Whh  = (const float*)d_in[3];
  const float* bih  = (const float*)d_in[4];
  const float* bhh  = (const float*)d_in[5];
  const float* hfcW = (const float*)d_in[6];
  const float* hfcb = (const float*)d_in[7];
  const float* cfcW = (const float*)d_in[8];
  const float* cfcb = (const float*)d_in[9];
  const float* midW = (const float*)d_in[10];
  const float* midb = (const float*)d_in[11];
  const float* o1W  = (const float*)d_in[12];
  const float* o1b  = (const float*)d_in[13];
  const float* o2W  = (const float*)d_in[14];
  const float* o2b  = (const float*)d_in[15];
  const float* o3W  = (const float*)d_in[16];
  const float* o3b  = (const float*)d_in[17];
  float* out = (float*)d_out;
  char*  ws  = (char*)d_ws;

  float* Gpre = (float*)(ws + 0);               // 1024 x 6144 fp32
  float* h1f  = (float*)(ws + 25165824);
  float* c1f  = (float*)(ws + 28311552);
  float* h2f  = (float*)(ws + 31457280);
  float* cp3f = (float*)(ws + 34603008);
  float* h3f  = (float*)(ws + 37748736);
  u16*   xh   = (u16*)(ws + 40894464);
  u16*   Wihh = (u16*)(ws + 42467328);          // all 3 tasks, 9216x768
  u16*   Whhh = (u16*)(ws + 56623104);          // Whh[1], Whh[2]
  u16*   hfch = (u16*)(ws + 66060288);
  u16*   cfch = (u16*)(ws + 67239936);
  u16*   midh = (u16*)(ws + 68419584);
  u16*   o1h  = (u16*)(ws + 71958528);
  u16*   o2h  = (u16*)(ws + 72268800);
  u16*   o3h  = (u16*)(ws + 72549888);
  u16*   h1h  = (u16*)(ws + 72566784);
  u16*   h2h  = (u16*)(ws + 74139648);
  u16*   c2h  = (u16*)(ws + 75712512);
  u16*   hp3h = (u16*)(ws + 77285376);
  u16*   a1h  = (u16*)(ws + 78858240);
  u16*   a2h  = (u16*)(ws + 80431104);
  u16*   a3h  = (u16*)(ws + 82003968);
  u16*   m1h  = (u16*)(ws + 83576832);
  u16*   m2h  = (u16*)(ws + 85149696);
  u16*   m3h  = (u16*)(ws + 86722560);
  // workspace end: 88,295,424 bytes

  // ---- K0: cvt x + Wih (needed by K1) ----
  cvt0_k<<<2048, 256, 0, stream>>>(x, xh, Wih, Wihh);

  // ---- K1: cell1 || Gpre || cvt-rest ----
  K1P p1;
  p1.xh = xh; p1.Wihh = Wihh; p1.bih = bih; p1.bhh = bhh;
  p1.h1f = h1f; p1.c1f = c1f; p1.h1h = h1h; p1.Gpre = Gpre;
  p1.Whh = Whh; p1.hfcW = hfcW; p1.cfcW = cfcW; p1.midW = midW;
  p1.o1W = o1W; p1.o2W = o2W; p1.o3W = o3W;
  p1.Whhh = Whhh; p1.hfch = hfch; p1.cfch = cfch; p1.midh = midh;
  p1.o1h = o1h; p1.o2h = o2h; p1.o3h = o3h;
  k1_k<<<1536, 256, 0, stream>>>(p1);

  // ---- K2: cell2: gates = Gpre[task2] + h1*Whh[1]^T ----
  cell_k<<<dim3(24, 16), 256, 0, stream>>>(h1h, Whhh, Gpre, c1f,
                                           h2f, nullptr, h2h, c2h);

  // ---- K3: hp3 = h1 + h2*hfcW^T + hfcb ; cp3 = c1 + c2*cfcW^T + cfcb ----
  GArgs P;
  P = GArgs{};
  P.j[0] = { h2h, hfch, nullptr, hp3h, hfcb, nullptr, h1f, 768, 768, 0 };
  P.j[1] = { c2h, cfch, cp3f, nullptr, cfcb, nullptr, c1f, 768, 768, 0 };
  P.j[2] = P.j[1];
  gemm_k<<<dim3(6, 16, 2), 256, 0, stream>>>(P);

  // ---- K4: cell3: gates = Gpre[task3] + hp3*Whh[2]^T ----
  cell_k<<<dim3(24, 16), 256, 0, stream>>>(hp3h, Whhh + 2359296, Gpre + 3072,
                                           cp3f, h3f, nullptr, nullptr, nullptr);

  // ---- K5: fused attention (single pass over attn) ----
  attn_k<<<1024, 256, 0, stream>>>(attn, h1f, h2f, h3f, a1h, a2h, a3h);

  // ---- K6: mid heads: m = relu(a*midW^T + midb) ----
  P = GArgs{};
  P.j[0] = { a1h, midh,           nullptr, m1h, midb,        nullptr, nullptr, 768, 768, 1 };
  P.j[1] = { a2h, midh +  589824, nullptr, m2h, midb +  768, nullptr, nullptr, 768, 768, 1 };
  P.j[2] = { a3h, midh + 1179648, nullptr, m3h, midb + 1536, nullptr, nullptr, 768, 768, 1 };
  gemm_k<<<dim3(6, 16, 3), 256, 0, stream>>>(P);

  // ---- K7: output heads ----
  P = GArgs{};
  P.j[0] = { m1h, o1h, out,          nullptr, o1b, nullptr, nullptr, 202, 202, 0 };
  P.j[1] = { m2h, o2h, out + 206848, nullptr, o2b, nullptr, nullptr, 183, 183, 0 };
  P.j[2] = { m3h, o3h, out + 394240, nullptr, o3b, nullptr, nullptr,  11,  11, 0 };
  gemm_k<<<dim3(2, 16, 3), 256, 0, stream>>>(P);

  (void)in_sizes; (void)n_in; (void)out_size; (void)ws_size;
}